// Round 11
// baseline (616.724 us; speedup 1.0000x reference)
//
#include <hip/hip_runtime.h>
#include <hip/hip_bf16.h>
#include <stdint.h>

#define T_TOK 4096
#define H_DIM 2048
#define I_DIM 1024
#define E_NUM 8
#define NPAIR 8192            // T_TOK * K_SEL
#define BM 128
#define MAX_TILES 72          // worst case sum(ceil(cnt_e/128)) = 64 + 7
#define CAP (MAX_TILES * BM)  // 9216 padded pair slots
#define NTB (MAX_TILES * 16)  // gemm grid = 1152 (16 nt bands of 128 cols)

// prep_all grid layout
#define CVT_BLKS 1024
#define GU_BLKS 4096          // 8192 gu 64x64 tiles, 2 per block
#define D_BLKS 2048           // 4096 d 64x64 tiles, 2 per block
#define PREP_BLKS (CVT_BLKS + GU_BLKS + D_BLKS + 1)

typedef short s16x8 __attribute__((ext_vector_type(8)));
typedef __bf16 bf16x8 __attribute__((ext_vector_type(8)));
typedef float f32x4 __attribute__((ext_vector_type(4)));

using gas1_t = const __attribute__((address_space(1))) void*;
using las3_t = __attribute__((address_space(3))) void*;

__device__ __forceinline__ void async_lds16(const void* g, void* l) {
  __builtin_amdgcn_global_load_lds((gas1_t)(uintptr_t)g,
                                   (las3_t)(uint32_t)(uintptr_t)l, 16, 0, 0);
}

__device__ __forceinline__ unsigned short f2bf(float f) {
  union { float f; unsigned int u; } v; v.f = f;
  unsigned int r = v.u + 0x7FFF + ((v.u >> 16) & 1); // RNE
  return (unsigned short)(r >> 16);
}

__device__ __forceinline__ f32x4 mfma_bf16(s16x8 a, s16x8 b, f32x4 c) {
  return __builtin_amdgcn_mfma_f32_16x16x32_bf16(
      __builtin_bit_cast(bf16x8, a), __builtin_bit_cast(bf16x8, b), c, 0, 0, 0);
}

__device__ __forceinline__ unsigned short gelu_mul_bf16(float g, float u) {
  const float z = 0.7978845608028654f * (g + 0.044715f * g * g * g);
  const float ex = __expf(2.f * z);
  const float th = (ex - 1.f) / (ex + 1.f);
  return f2bf(0.5f * g * (1.f + th) * u);
}

__device__ __forceinline__ float bflo(unsigned int u) {
  return __uint_as_float(u << 16);
}
__device__ __forceinline__ float bfhi(unsigned int u) {
  return __uint_as_float(u & 0xFFFF0000u);
}

// ===== prep: cvt x + transpose(Wg,Wu->WguT) + transpose(Wd->WdT) + routing ==
// (identical to round-5..8 passing version; LDS stride 73 = conflict-free)
__global__ __launch_bounds__(512)
void prep_all(const float4* __restrict__ x4, ushort4* __restrict__ xb4,
              const float* __restrict__ Wg, const float* __restrict__ Wu,
              const float* __restrict__ Wd,
              unsigned short* __restrict__ WguT,
              unsigned short* __restrict__ WdT,
              const int* __restrict__ sel, const float* __restrict__ rw,
              int* __restrict__ pair_token, float* __restrict__ pair_weight,
              int* __restrict__ inv,
              int* __restrict__ tile_expert, int* __restrict__ tile_pos) {
  const int bid = blockIdx.x;
  const int tid = threadIdx.x;

  if (bid < CVT_BLKS) {                    // ---- cvt x -> bf16 ----
    int i = bid * 512 + tid;
    const int stride = CVT_BLKS * 512;
#pragma unroll
    for (int q = 0; q < 4; ++q) {
      const float4 v = x4[i];
      ushort4 r;
      r.x = f2bf(v.x); r.y = f2bf(v.y); r.z = f2bf(v.z); r.w = f2bf(v.w);
      xb4[i] = r;
      i += stride;
    }
    return;
  }

  if (bid < CVT_BLKS + GU_BLKS + D_BLKS) { // ---- weight transposes ----
    __shared__ unsigned short Tl[2][64 * 73];
    const int sub = tid >> 8, k = tid & 255;
    const int rr = k >> 2, cb = (k & 3) * 16;
    const int oc = k >> 2, rb = (k & 3) * 16;

    if (bid < CVT_BLKS + GU_BLKS) {        // Wg/Wu -> WguT (g/u interleaved)
      const int t3 = (bid - CVT_BLKS) * 2 + sub;    // [0, 8192)
      const int which = t3 >> 12;                   // 0=gate, 1=up
      const int e = (t3 >> 9) & 7;
      const int tile = t3 & 511;                    // 32 h-tiles x 16 i-tiles
      const int r0 = (tile >> 4) * 64;              // h base
      const int c0 = (tile & 15) * 64;              // i base
      const float* src = (which ? Wu : Wg) + (size_t)e * H_DIM * I_DIM;
      const float4* s4 = (const float4*)(src + (size_t)(r0 + rr) * I_DIM + c0 + cb);
      unsigned short* dl = &Tl[sub][rr * 73 + cb];
#pragma unroll
      for (int q = 0; q < 4; ++q) {
        const float4 v = s4[q];
        dl[q * 4 + 0] = f2bf(v.x); dl[q * 4 + 1] = f2bf(v.y);
        dl[q * 4 + 2] = f2bf(v.z); dl[q * 4 + 3] = f2bf(v.w);
      }
      __syncthreads();
      union { unsigned short us[16]; uint4 u4[2]; } pk;
#pragma unroll
      for (int m = 0; m < 16; ++m) pk.us[m] = Tl[sub][(rb + m) * 73 + oc];
      const int gi = c0 + oc;
      const int orow = (gi >> 4) * 32 + (gi & 15) + which * 16;
      uint4* d4 = (uint4*)(WguT + ((size_t)e * 2048 + orow) * H_DIM + r0 + rb);
      d4[0] = pk.u4[0]; d4[1] = pk.u4[1];
    } else {                               // Wd -> WdT (i'-permuted cols)
      const int t3 = (bid - CVT_BLKS - GU_BLKS) * 2 + sub;  // [0, 4096)
      const int e = t3 >> 9;
      const int tile = t3 & 511;                    // 16 i-tiles x 32 h-tiles
      const int r0 = (tile >> 5) * 64;              // i base
      const int c0 = (tile & 31) * 64;              // h base
      const float* src = Wd + (size_t)e * I_DIM * H_DIM;
      const float4* s4 = (const float4*)(src + (size_t)(r0 + rr) * H_DIM + c0 + cb);
      unsigned short* dl = &Tl[sub][rr * 73 + cb];
#pragma unroll
      for (int q = 0; q < 4; ++q) {
        const float4 v = s4[q];
        dl[q * 4 + 0] = f2bf(v.x); dl[q * 4 + 1] = f2bf(v.y);
        dl[q * 4 + 2] = f2bf(v.z); dl[q * 4 + 3] = f2bf(v.w);
      }
      __syncthreads();
      union { unsigned short us[16]; uint4 u4[2]; } pk;
#pragma unroll
      for (int m = 0; m < 16; ++m) {
        const int il = rb + m;                      // i' local [0,64)
        const int isrc = (il & 32) + ((il & 1) << 4) + ((il >> 1) & 15);
        pk.us[m] = Tl[sub][isrc * 73 + oc];
      }
      const int gh = c0 + oc;
      uint4* d4 = (uint4*)(WdT + ((size_t)e * H_DIM + gh) * I_DIM + r0 + rb);
      d4[0] = pk.u4[0]; d4[1] = pk.u4[1];
    }
    return;
  }

  // ---- routing (single block), BM=128 tiles ----
  __shared__ int cnt[E_NUM], off[E_NUM], fil[E_NUM];
  if (tid < E_NUM) { cnt[tid] = 0; fil[tid] = 0; }
  __syncthreads();
  for (int p = tid; p < NPAIR; p += 512) atomicAdd(&cnt[sel[p]], 1);
  for (int q = tid; q < CAP; q += 512) { pair_token[q] = 0; pair_weight[q] = 0.f; }
  __syncthreads();
  if (tid == 0) {
    int run = 0, idx = 0;
    for (int e = 0; e < E_NUM; ++e) {
      off[e] = run;
      const int nt = (cnt[e] + BM - 1) / BM;
      for (int t = 0; t < nt; ++t) { tile_expert[idx] = e; tile_pos[idx] = run + t * BM; ++idx; }
      run += nt * BM;
    }
    for (; idx < MAX_TILES; ++idx) tile_expert[idx] = -1;
  }
  __syncthreads();
  for (int p = tid; p < NPAIR; p += 512) {
    const int e = sel[p];
    const int pos = off[e] + atomicAdd(&fil[e], 1);
    pair_token[pos] = p >> 1;   // K_SEL == 2
    pair_weight[pos] = rw[p];
    inv[p] = pos;
  }
}

// ====== 128x128 GEMM, 256 thr, single-buffer 32KB LDS, OCCUPANCY 4 ========
// MODE 0: A = xb gathered by pair_token (K=2048), B = WguT -> a_pair packed u32
// MODE 1: A = a_pair (K=1024, i' order), B = WdT -> d_pair bf16 (w applied)
// Rate law (r4..r10 + m97/m102 fits): global_load_lds delivers ~7-8 B/cyc per
// RESIDENT BLOCK. So: small tile, 32KB LDS, VGPR<=128 (launch_bounds(256,4))
// -> 4 blocks/CU -> ~30 B/cyc/CU aggregate. In-block vmcnt(0) serialization
// is hidden by cross-block TLP (m114/m97 mechanism).
template<int MODE>
__global__ __launch_bounds__(256, 4)
void moe_gemm(const unsigned short* __restrict__ Aop,
              const unsigned short* __restrict__ Bop,
              const int* __restrict__ pair_token,
              const float* __restrict__ pair_weight,
              const int* __restrict__ tile_expert,
              const int* __restrict__ tile_pos,
              unsigned int* __restrict__ a32,
              unsigned short* __restrict__ d_pair) {
  constexpr int KD = (MODE == 0) ? H_DIM : I_DIM;
  constexpr int NT = KD / 64;

  __shared__ unsigned short sA[128 * 64];   // 16 KB
  __shared__ unsigned short sB[128 * 64];   // 16 KB

  const int bid = blockIdx.x;
  const int lgc = (bid & 7) * (NTB / 8) + (bid >> 3);   // XCD-chunked, bijective
  const int mt = lgc >> 4;
  const int nt = lgc & 15;               // nt fastest within XCD: A-tile reuse
  const int e = tile_expert[mt];
  if (e < 0) return;
  const int pbase = tile_pos[mt];

  const int tid = threadIdx.x;
  const int wv = tid >> 6;               // 0..3
  const int lane = tid & 63;
  const int fr = lane & 15;
  const int fq = lane >> 4;
  const int wm = (wv >> 1) * 64;         // 0/64
  const int wnh = wv & 1;                // 0/1 -> wn = wnh*64

  // staging sources: 4 gloads/operand/thread; call j covers rows (wv*4+j)*8+(l>>3)
  const int rloc = lane >> 3;            // 0..7
  const int gch = (lane & 7) ^ rloc;     // pre-swizzled chunk (row&7 == rloc)
  const unsigned short* pa[4];
  const unsigned short* pb[4];
#pragma unroll
  for (int j = 0; j < 4; ++j) {
    const int row = (wv * 4 + j) * 8 + rloc;  // 0..127
    size_t arow;
    if constexpr (MODE == 0) arow = (size_t)pair_token[pbase + row];
    else                     arow = (size_t)(pbase + row);
    pa[j] = Aop + arow * KD + gch * 8;
    pb[j] = Bop + ((size_t)e * 2048 + nt * 128 + row) * KD + gch * 8;
  }

  // LDS fragment offsets (shorts); row stride = 64 shorts, XOR chunk swizzle
  int aoff[4][2], boff[4][2];
#pragma unroll
  for (int mf = 0; mf < 4; ++mf)
#pragma unroll
    for (int kk = 0; kk < 2; ++kk) {
      const int ra = wm + mf * 16 + fr;
      aoff[mf][kk] = ra * 64 + (((kk * 4 + fq) ^ (ra & 7)) * 8);
      const int rb = wnh * 64 + mf * 16 + fr;
      boff[mf][kk] = rb * 64 + (((kk * 4 + fq) ^ (rb & 7)) * 8);
    }

  f32x4 acc[4][4] = {};

  for (int t = 0; t < NT; ++t) {
    // stage tile t (single buffer)
    {
      const int o = wv * 2048;
#pragma unroll
      for (int j = 0; j < 4; ++j) {
        async_lds16(pa[j] + (size_t)t * 64, sA + o + j * 512);
        async_lds16(pb[j] + (size_t)t * 64, sB + o + j * 512);
      }
    }
    asm volatile("s_waitcnt vmcnt(0)" ::: "memory");
    __builtin_amdgcn_s_barrier();

    s16x8 aF[4][2], bF[4][2];
#pragma unroll
    for (int mf = 0; mf < 4; ++mf)
#pragma unroll
      for (int kk = 0; kk < 2; ++kk) {
        aF[mf][kk] = *(const s16x8*)&sA[aoff[mf][kk]];
        bF[mf][kk] = *(const s16x8*)&sB[boff[mf][kk]];
      }
    __builtin_amdgcn_s_setprio(1);
#pragma unroll
    for (int kk = 0; kk < 2; ++kk)
#pragma unroll
      for (int mf = 0; mf < 4; ++mf)
#pragma unroll
        for (int nf = 0; nf < 4; ++nf)
          acc[mf][nf] = mfma_bf16(aF[mf][kk], bF[nf][kk], acc[mf][nf]);
    __builtin_amdgcn_s_setprio(0);
    __builtin_amdgcn_s_barrier();   // all reads consumed before next overwrite
  }

  if constexpr (MODE == 0) {
    // packed epilogue: acc cols (0,1)=(g,u) of i0, (2,3)=(g,u) of i1=i0+16
    const int cidx = nt * 32 + wnh * 16 + fr;   // dword index within row
#pragma unroll
    for (int mf = 0; mf < 4; ++mf)
#pragma unroll
      for (int jj = 0; jj < 4; ++jj) {
        const int row = pbase + wm + mf * 16 + fq * 4 + jj;
        const unsigned int h0 = gelu_mul_bf16(acc[mf][0][jj], acc[mf][1][jj]);
        const unsigned int h1 = gelu_mul_bf16(acc[mf][2][jj], acc[mf][3][jj]);
        a32[(size_t)row * (I_DIM / 2) + cidx] = h0 | (h1 << 16);
      }
  } else {
    // plain bf16 stores of w*d into d_pair (combine sums the two experts)
#pragma unroll
    for (int mf = 0; mf < 4; ++mf)
#pragma unroll
      for (int jj = 0; jj < 4; ++jj) {
        const int prow = pbase + wm + mf * 16 + fq * 4 + jj;
        const float w = pair_weight[prow];
        unsigned short* dp = d_pair + (size_t)prow * H_DIM + nt * 128 + wnh * 64 + fr;
#pragma unroll
        for (int nf = 0; nf < 4; ++nf)
          dp[nf * 16] = f2bf(w * acc[mf][nf][jj]);
      }
  }
}

// ========================= combine: out[t] = d[p0] + d[p1] =================
__global__ __launch_bounds__(256)
void combine(const unsigned short* __restrict__ d_pair,
             const int* __restrict__ inv,
             float* __restrict__ out) {
  const int tid = threadIdx.x;
  const int tok = blockIdx.x * 2 + (tid >> 7);
  const int ln = tid & 127;
  const int p0 = inv[2 * tok], p1 = inv[2 * tok + 1];
  const uint4* r0 = (const uint4*)(d_pair + (size_t)p0 * H_DIM);
  const uint4* r1 = (const uint4*)(d_pair + (size_t)p1 * H_DIM);
  float4* o = (float4*)(out + (size_t)tok * H_DIM);
#pragma unroll
  for (int j = 0; j < 2; ++j) {
    const int c = ln + j * 128;               // uint4 index, 256 per row
    const uint4 a = r0[c];
    const uint4 b = r1[c];
    float4 fa, fb;
    fa.x = bflo(a.x) + bflo(b.x); fa.y = bfhi(a.x) + bfhi(b.x);
    fa.z = bflo(a.y) + bflo(b.y); fa.w = bfhi(a.y) + bfhi(b.y);
    fb.x = bflo(a.z) + bflo(b.z); fb.y = bfhi(a.z) + bfhi(b.z);
    fb.z = bflo(a.w) + bflo(b.w); fb.w = bfhi(a.w) + bfhi(b.w);
    o[2 * c] = fa;
    o[2 * c + 1] = fb;
  }
}

// ================================= launch ==================================
extern "C" void kernel_launch(void* const* d_in, const int* in_sizes, int n_in,
                              void* d_out, int out_size, void* d_ws, size_t ws_size,
                              hipStream_t stream) {
  const float* x  = (const float*)d_in[0];
  const float* Wg = (const float*)d_in[1];
  const float* Wu = (const float*)d_in[2];
  const float* Wd = (const float*)d_in[3];
  const int*   sel = (const int*)d_in[4];
  const float* rw  = (const float*)d_in[5];
  float* out = (float*)d_out;

  char* base = (char*)d_ws;
  size_t off = 0;
  auto take = [&](size_t bytes) { char* p = base + off; off += bytes; return p; };
  unsigned short* xb     = (unsigned short*)take((size_t)T_TOK * H_DIM * 2);
  unsigned short* WguT   = (unsigned short*)take((size_t)E_NUM * 2048 * H_DIM * 2);
  unsigned short* WdT    = (unsigned short*)take((size_t)E_NUM * H_DIM * I_DIM * 2);
  unsigned short* a_pair = (unsigned short*)take((size_t)CAP * I_DIM * 2);
  unsigned short* d_pair = (unsigned short*)take((size_t)CAP * H_DIM * 2);
  int*   pair_token  = (int*)take(CAP * 4);
  float* pair_weight = (float*)take(CAP * 4);
  int*   inv         = (int*)take(NPAIR * 4);
  int*   tile_expert = (int*)take(512);
  int*   tile_pos    = (int*)take(512);
  (void)off;

  prep_all<<<PREP_BLKS, 512, 0, stream>>>(
      (const float4*)x, (ushort4*)xb, Wg, Wu, Wd, WguT, WdT, sel, rw,
      pair_token, pair_weight, inv, tile_expert, tile_pos);

  moe_gemm<0><<<NTB, 256, 0, stream>>>(
      xb, WguT, pair_token, pair_weight, tile_expert, tile_pos,
      (unsigned int*)a_pair, nullptr);

  moe_gemm<1><<<NTB, 256, 0, stream>>>(
      a_pair, WdT, pair_token, pair_weight, tile_expert, tile_pos,
      nullptr, d_pair);

  combine<<<T_TOK / 2, 256, 0, stream>>>(d_pair, inv, out);
}

// Round 12
// 274.725 us; speedup vs baseline: 2.2449x; 2.2449x over previous
//
#include <hip/hip_runtime.h>
#include <hip/hip_bf16.h>
#include <stdint.h>

#define T_TOK 4096
#define H_DIM 2048
#define I_DIM 1024
#define E_NUM 8
#define NPAIR 8192            // T_TOK * K_SEL
#define BM 128
#define MAX_TILES 72          // worst case sum(ceil(cnt_e/128)) = 64 + 7
#define CAP (MAX_TILES * BM)  // 9216 padded pair slots
#define NTB (MAX_TILES * 16)  // gemm grid = 1152 (16 nt bands of 128 cols)

// prep_all grid layout
#define CVT_BLKS 1024
#define GU_BLKS 4096          // 8192 gu 64x64 tiles, 2 per block
#define D_BLKS 2048           // 4096 d 64x64 tiles, 2 per block
#define PREP_BLKS (CVT_BLKS + GU_BLKS + D_BLKS + 1)

typedef short s16x8 __attribute__((ext_vector_type(8)));
typedef __bf16 bf16x8 __attribute__((ext_vector_type(8)));
typedef float f32x4 __attribute__((ext_vector_type(4)));

using gas1_t = const __attribute__((address_space(1))) void*;
using las3_t = __attribute__((address_space(3))) void*;

__device__ __forceinline__ void async_lds16(const void* g, void* l) {
  __builtin_amdgcn_global_load_lds((gas1_t)(uintptr_t)g,
                                   (las3_t)(uint32_t)(uintptr_t)l, 16, 0, 0);
}

__device__ __forceinline__ unsigned short f2bf(float f) {
  union { float f; unsigned int u; } v; v.f = f;
  unsigned int r = v.u + 0x7FFF + ((v.u >> 16) & 1); // RNE
  return (unsigned short)(r >> 16);
}

__device__ __forceinline__ f32x4 mfma_bf16(s16x8 a, s16x8 b, f32x4 c) {
  return __builtin_amdgcn_mfma_f32_16x16x32_bf16(
      __builtin_bit_cast(bf16x8, a), __builtin_bit_cast(bf16x8, b), c, 0, 0, 0);
}

__device__ __forceinline__ unsigned short gelu_mul_bf16(float g, float u) {
  const float z = 0.7978845608028654f * (g + 0.044715f * g * g * g);
  const float ex = __expf(2.f * z);
  const float th = (ex - 1.f) / (ex + 1.f);
  return f2bf(0.5f * g * (1.f + th) * u);
}

__device__ __forceinline__ float bflo(unsigned int u) {
  return __uint_as_float(u << 16);
}
__device__ __forceinline__ float bfhi(unsigned int u) {
  return __uint_as_float(u & 0xFFFF0000u);
}

// ===== prep: cvt x + transpose(Wg,Wu->WguT) + transpose(Wd->WdT) + routing ==
// (identical to round-5..8 passing version; LDS stride 73 = conflict-free)
__global__ __launch_bounds__(512)
void prep_all(const float4* __restrict__ x4, ushort4* __restrict__ xb4,
              const float* __restrict__ Wg, const float* __restrict__ Wu,
              const float* __restrict__ Wd,
              unsigned short* __restrict__ WguT,
              unsigned short* __restrict__ WdT,
              const int* __restrict__ sel, const float* __restrict__ rw,
              int* __restrict__ pair_token, float* __restrict__ pair_weight,
              int* __restrict__ inv,
              int* __restrict__ tile_expert, int* __restrict__ tile_pos) {
  const int bid = blockIdx.x;
  const int tid = threadIdx.x;

  if (bid < CVT_BLKS) {                    // ---- cvt x -> bf16 ----
    int i = bid * 512 + tid;
    const int stride = CVT_BLKS * 512;
#pragma unroll
    for (int q = 0; q < 4; ++q) {
      const float4 v = x4[i];
      ushort4 r;
      r.x = f2bf(v.x); r.y = f2bf(v.y); r.z = f2bf(v.z); r.w = f2bf(v.w);
      xb4[i] = r;
      i += stride;
    }
    return;
  }

  if (bid < CVT_BLKS + GU_BLKS + D_BLKS) { // ---- weight transposes ----
    __shared__ unsigned short Tl[2][64 * 73];
    const int sub = tid >> 8, k = tid & 255;
    const int rr = k >> 2, cb = (k & 3) * 16;
    const int oc = k >> 2, rb = (k & 3) * 16;

    if (bid < CVT_BLKS + GU_BLKS) {        // Wg/Wu -> WguT (g/u interleaved)
      const int t3 = (bid - CVT_BLKS) * 2 + sub;    // [0, 8192)
      const int which = t3 >> 12;                   // 0=gate, 1=up
      const int e = (t3 >> 9) & 7;
      const int tile = t3 & 511;                    // 32 h-tiles x 16 i-tiles
      const int r0 = (tile >> 4) * 64;              // h base
      const int c0 = (tile & 15) * 64;              // i base
      const float* src = (which ? Wu : Wg) + (size_t)e * H_DIM * I_DIM;
      const float4* s4 = (const float4*)(src + (size_t)(r0 + rr) * I_DIM + c0 + cb);
      unsigned short* dl = &Tl[sub][rr * 73 + cb];
#pragma unroll
      for (int q = 0; q < 4; ++q) {
        const float4 v = s4[q];
        dl[q * 4 + 0] = f2bf(v.x); dl[q * 4 + 1] = f2bf(v.y);
        dl[q * 4 + 2] = f2bf(v.z); dl[q * 4 + 3] = f2bf(v.w);
      }
      __syncthreads();
      union { unsigned short us[16]; uint4 u4[2]; } pk;
#pragma unroll
      for (int m = 0; m < 16; ++m) pk.us[m] = Tl[sub][(rb + m) * 73 + oc];
      const int gi = c0 + oc;
      const int orow = (gi >> 4) * 32 + (gi & 15) + which * 16;
      uint4* d4 = (uint4*)(WguT + ((size_t)e * 2048 + orow) * H_DIM + r0 + rb);
      d4[0] = pk.u4[0]; d4[1] = pk.u4[1];
    } else {                               // Wd -> WdT (i'-permuted cols)
      const int t3 = (bid - CVT_BLKS - GU_BLKS) * 2 + sub;  // [0, 4096)
      const int e = t3 >> 9;
      const int tile = t3 & 511;                    // 16 i-tiles x 32 h-tiles
      const int r0 = (tile >> 5) * 64;              // i base
      const int c0 = (tile & 31) * 64;              // h base
      const float* src = Wd + (size_t)e * I_DIM * H_DIM;
      const float4* s4 = (const float4*)(src + (size_t)(r0 + rr) * H_DIM + c0 + cb);
      unsigned short* dl = &Tl[sub][rr * 73 + cb];
#pragma unroll
      for (int q = 0; q < 4; ++q) {
        const float4 v = s4[q];
        dl[q * 4 + 0] = f2bf(v.x); dl[q * 4 + 1] = f2bf(v.y);
        dl[q * 4 + 2] = f2bf(v.z); dl[q * 4 + 3] = f2bf(v.w);
      }
      __syncthreads();
      union { unsigned short us[16]; uint4 u4[2]; } pk;
#pragma unroll
      for (int m = 0; m < 16; ++m) {
        const int il = rb + m;                      // i' local [0,64)
        const int isrc = (il & 32) + ((il & 1) << 4) + ((il >> 1) & 15);
        pk.us[m] = Tl[sub][isrc * 73 + oc];
      }
      const int gh = c0 + oc;
      uint4* d4 = (uint4*)(WdT + ((size_t)e * H_DIM + gh) * I_DIM + r0 + rb);
      d4[0] = pk.u4[0]; d4[1] = pk.u4[1];
    }
    return;
  }

  // ---- routing (single block), BM=128 tiles ----
  __shared__ int cnt[E_NUM], off[E_NUM], fil[E_NUM];
  if (tid < E_NUM) { cnt[tid] = 0; fil[tid] = 0; }
  __syncthreads();
  for (int p = tid; p < NPAIR; p += 512) atomicAdd(&cnt[sel[p]], 1);
  for (int q = tid; q < CAP; q += 512) { pair_token[q] = 0; pair_weight[q] = 0.f; }
  __syncthreads();
  if (tid == 0) {
    int run = 0, idx = 0;
    for (int e = 0; e < E_NUM; ++e) {
      off[e] = run;
      const int nt = (cnt[e] + BM - 1) / BM;
      for (int t = 0; t < nt; ++t) { tile_expert[idx] = e; tile_pos[idx] = run + t * BM; ++idx; }
      run += nt * BM;
    }
    for (; idx < MAX_TILES; ++idx) tile_expert[idx] = -1;
  }
  __syncthreads();
  for (int p = tid; p < NPAIR; p += 512) {
    const int e = sel[p];
    const int pos = off[e] + atomicAdd(&fil[e], 1);
    pair_token[pos] = p >> 1;   // K_SEL == 2
    pair_weight[pos] = rw[p];
    inv[p] = pos;
  }
}

// ====== 128x128 GEMM, 256 thr, single-buffer 32KB LDS, 5 blocks/CU =========
// MODE 0: A = xb gathered by pair_token (K=2048), B = WguT -> a_pair packed u32
// MODE 1: A = a_pair (K=1024, i' order), B = WdT -> d_pair bf16 (w applied)
// Rate law (r4..r11 + m97 fits): staging throughput ~1.7-1.9 B/cyc per
// RESIDENT WAVE. 32KB LDS + VGPR~80 (launch_bounds(256,2), r4-proven; the
// (256,4) of r11 forced VGPR=64 -> 0.5GB scratch spill) -> 5 blocks/CU =
// 20 waves -> ~35 B/cyc/CU. In-block vmcnt(0) serialization hidden by TLP.
template<int MODE>
__global__ __launch_bounds__(256, 2)
void moe_gemm(const unsigned short* __restrict__ Aop,
              const unsigned short* __restrict__ Bop,
              const int* __restrict__ pair_token,
              const float* __restrict__ pair_weight,
              const int* __restrict__ tile_expert,
              const int* __restrict__ tile_pos,
              unsigned int* __restrict__ a32,
              unsigned short* __restrict__ d_pair) {
  constexpr int KD = (MODE == 0) ? H_DIM : I_DIM;
  constexpr int NT = KD / 64;

  __shared__ unsigned short sA[128 * 64];   // 16 KB
  __shared__ unsigned short sB[128 * 64];   // 16 KB

  const int bid = blockIdx.x;
  const int lgc = (bid & 7) * (NTB / 8) + (bid >> 3);   // XCD-chunked, bijective
  const int mt = lgc >> 4;
  const int nt = lgc & 15;               // nt fastest within XCD: A-tile reuse
  const int e = tile_expert[mt];
  if (e < 0) return;
  const int pbase = tile_pos[mt];

  const int tid = threadIdx.x;
  const int wv = tid >> 6;               // 0..3
  const int lane = tid & 63;
  const int fr = lane & 15;
  const int fq = lane >> 4;
  const int wm = (wv >> 1) * 64;         // 0/64
  const int wnh = wv & 1;                // 0/1 -> wn = wnh*64

  // staging sources: 4 gloads/operand/thread; call j covers rows (wv*4+j)*8+(l>>3)
  const int rloc = lane >> 3;            // 0..7
  const int gch = (lane & 7) ^ rloc;     // pre-swizzled chunk (row&7 == rloc)
  const unsigned short* pa[4];
  const unsigned short* pb[4];
#pragma unroll
  for (int j = 0; j < 4; ++j) {
    const int row = (wv * 4 + j) * 8 + rloc;  // 0..127
    size_t arow;
    if constexpr (MODE == 0) arow = (size_t)pair_token[pbase + row];
    else                     arow = (size_t)(pbase + row);
    pa[j] = Aop + arow * KD + gch * 8;
    pb[j] = Bop + ((size_t)e * 2048 + nt * 128 + row) * KD + gch * 8;
  }

  // LDS fragment offsets (shorts); row stride = 64 shorts, XOR chunk swizzle
  int aoff[4][2], boff[4][2];
#pragma unroll
  for (int mf = 0; mf < 4; ++mf)
#pragma unroll
    for (int kk = 0; kk < 2; ++kk) {
      const int ra = wm + mf * 16 + fr;
      aoff[mf][kk] = ra * 64 + (((kk * 4 + fq) ^ (ra & 7)) * 8);
      const int rb = wnh * 64 + mf * 16 + fr;
      boff[mf][kk] = rb * 64 + (((kk * 4 + fq) ^ (rb & 7)) * 8);
    }

  f32x4 acc[4][4] = {};

  for (int t = 0; t < NT; ++t) {
    // stage tile t (single buffer)
    {
      const int o = wv * 2048;
#pragma unroll
      for (int j = 0; j < 4; ++j) {
        async_lds16(pa[j] + (size_t)t * 64, sA + o + j * 512);
        async_lds16(pb[j] + (size_t)t * 64, sB + o + j * 512);
      }
    }
    asm volatile("s_waitcnt vmcnt(0)" ::: "memory");
    __builtin_amdgcn_s_barrier();

    s16x8 aF[4][2], bF[4][2];
#pragma unroll
    for (int mf = 0; mf < 4; ++mf)
#pragma unroll
      for (int kk = 0; kk < 2; ++kk) {
        aF[mf][kk] = *(const s16x8*)&sA[aoff[mf][kk]];
        bF[mf][kk] = *(const s16x8*)&sB[boff[mf][kk]];
      }
    __builtin_amdgcn_s_setprio(1);
#pragma unroll
    for (int kk = 0; kk < 2; ++kk)
#pragma unroll
      for (int mf = 0; mf < 4; ++mf)
#pragma unroll
        for (int nf = 0; nf < 4; ++nf)
          acc[mf][nf] = mfma_bf16(aF[mf][kk], bF[nf][kk], acc[mf][nf]);
    __builtin_amdgcn_s_setprio(0);
    __builtin_amdgcn_s_barrier();   // all reads consumed before next overwrite
  }

  if constexpr (MODE == 0) {
    // packed epilogue: acc cols (0,1)=(g,u) of i0, (2,3)=(g,u) of i1=i0+16
    const int cidx = nt * 32 + wnh * 16 + fr;   // dword index within row
#pragma unroll
    for (int mf = 0; mf < 4; ++mf)
#pragma unroll
      for (int jj = 0; jj < 4; ++jj) {
        const int row = pbase + wm + mf * 16 + fq * 4 + jj;
        const unsigned int h0 = gelu_mul_bf16(acc[mf][0][jj], acc[mf][1][jj]);
        const unsigned int h1 = gelu_mul_bf16(acc[mf][2][jj], acc[mf][3][jj]);
        a32[(size_t)row * (I_DIM / 2) + cidx] = h0 | (h1 << 16);
      }
  } else {
    // plain bf16 stores of w*d into d_pair (combine sums the two experts)
#pragma unroll
    for (int mf = 0; mf < 4; ++mf)
#pragma unroll
      for (int jj = 0; jj < 4; ++jj) {
        const int prow = pbase + wm + mf * 16 + fq * 4 + jj;
        const float w = pair_weight[prow];
        unsigned short* dp = d_pair + (size_t)prow * H_DIM + nt * 128 + wnh * 64 + fr;
#pragma unroll
        for (int nf = 0; nf < 4; ++nf)
          dp[nf * 16] = f2bf(w * acc[mf][nf][jj]);
      }
  }
}

// ========================= combine: out[t] = d[p0] + d[p1] =================
__global__ __launch_bounds__(256)
void combine(const unsigned short* __restrict__ d_pair,
             const int* __restrict__ inv,
             float* __restrict__ out) {
  const int tid = threadIdx.x;
  const int tok = blockIdx.x * 2 + (tid >> 7);
  const int ln = tid & 127;
  const int p0 = inv[2 * tok], p1 = inv[2 * tok + 1];
  const uint4* r0 = (const uint4*)(d_pair + (size_t)p0 * H_DIM);
  const uint4* r1 = (const uint4*)(d_pair + (size_t)p1 * H_DIM);
  float4* o = (float4*)(out + (size_t)tok * H_DIM);
#pragma unroll
  for (int j = 0; j < 2; ++j) {
    const int c = ln + j * 128;               // uint4 index, 256 per row
    const uint4 a = r0[c];
    const uint4 b = r1[c];
    float4 fa, fb;
    fa.x = bflo(a.x) + bflo(b.x); fa.y = bfhi(a.x) + bfhi(b.x);
    fa.z = bflo(a.y) + bflo(b.y); fa.w = bfhi(a.y) + bfhi(b.y);
    fb.x = bflo(a.z) + bflo(b.z); fb.y = bfhi(a.z) + bfhi(b.z);
    fb.z = bflo(a.w) + bflo(b.w); fb.w = bfhi(a.w) + bfhi(b.w);
    o[2 * c] = fa;
    o[2 * c + 1] = fb;
  }
}

// ================================= launch ==================================
extern "C" void kernel_launch(void* const* d_in, const int* in_sizes, int n_in,
                              void* d_out, int out_size, void* d_ws, size_t ws_size,
                              hipStream_t stream) {
  const float* x  = (const float*)d_in[0];
  const float* Wg = (const float*)d_in[1];
  const float* Wu = (const float*)d_in[2];
  const float* Wd = (const float*)d_in[3];
  const int*   sel = (const int*)d_in[4];
  const float* rw  = (const float*)d_in[5];
  float* out = (float*)d_out;

  char* base = (char*)d_ws;
  size_t off = 0;
  auto take = [&](size_t bytes) { char* p = base + off; off += bytes; return p; };
  unsigned short* xb     = (unsigned short*)take((size_t)T_TOK * H_DIM * 2);
  unsigned short* WguT   = (unsigned short*)take((size_t)E_NUM * 2048 * H_DIM * 2);
  unsigned short* WdT    = (unsigned short*)take((size_t)E_NUM * H_DIM * I_DIM * 2);
  unsigned short* a_pair = (unsigned short*)take((size_t)CAP * I_DIM * 2);
  unsigned short* d_pair = (unsigned short*)take((size_t)CAP * H_DIM * 2);
  int*   pair_token  = (int*)take(CAP * 4);
  float* pair_weight = (float*)take(CAP * 4);
  int*   inv         = (int*)take(NPAIR * 4);
  int*   tile_expert = (int*)take(512);
  int*   tile_pos    = (int*)take(512);
  (void)off;

  prep_all<<<PREP_BLKS, 512, 0, stream>>>(
      (const float4*)x, (ushort4*)xb, Wg, Wu, Wd, WguT, WdT, sel, rw,
      pair_token, pair_weight, inv, tile_expert, tile_pos);

  moe_gemm<0><<<NTB, 256, 0, stream>>>(
      xb, WguT, pair_token, pair_weight, tile_expert, tile_pos,
      (unsigned int*)a_pair, nullptr);

  moe_gemm<1><<<NTB, 256, 0, stream>>>(
      a_pair, WdT, pair_token, pair_weight, tile_expert, tile_pos,
      nullptr, d_pair);

  combine<<<T_TOK / 2, 256, 0, stream>>>(d_pair, inv, out);
}

// Round 13
// 267.083 us; speedup vs baseline: 2.3091x; 1.0286x over previous
//
#include <hip/hip_runtime.h>
#include <hip/hip_bf16.h>
#include <stdint.h>

#define T_TOK 4096
#define H_DIM 2048
#define I_DIM 1024
#define E_NUM 8
#define NPAIR 8192            // T_TOK * K_SEL
#define BM 128
#define MAX_TILES 72          // worst case sum(ceil(cnt_e/128)) = 64 + 7
#define CAP (MAX_TILES * BM)  // 9216 padded pair slots
#define NTB2 (MAX_TILES * 8)  // gemm grid = 576 (8 nt of 256 cols)

// prep_all grid layout
#define CVT_BLKS 1024
#define GU_BLKS 4096          // 8192 gu 64x64 tiles, 2 per block
#define D_BLKS 2048           // 4096 d 64x64 tiles, 2 per block
#define PREP_BLKS (CVT_BLKS + GU_BLKS + D_BLKS + 1)

typedef short s16x8 __attribute__((ext_vector_type(8)));
typedef __bf16 bf16x8 __attribute__((ext_vector_type(8)));
typedef float f32x4 __attribute__((ext_vector_type(4)));

using gas1_t = const __attribute__((address_space(1))) void*;
using las3_t = __attribute__((address_space(3))) void*;

__device__ __forceinline__ void async_lds16(const void* g, void* l) {
  __builtin_amdgcn_global_load_lds((gas1_t)(uintptr_t)g,
                                   (las3_t)(uint32_t)(uintptr_t)l, 16, 0, 0);
}

__device__ __forceinline__ unsigned short f2bf(float f) {
  union { float f; unsigned int u; } v; v.f = f;
  unsigned int r = v.u + 0x7FFF + ((v.u >> 16) & 1); // RNE
  return (unsigned short)(r >> 16);
}

__device__ __forceinline__ f32x4 mfma_bf16(s16x8 a, s16x8 b, f32x4 c) {
  return __builtin_amdgcn_mfma_f32_16x16x32_bf16(
      __builtin_bit_cast(bf16x8, a), __builtin_bit_cast(bf16x8, b), c, 0, 0, 0);
}

__device__ __forceinline__ unsigned short gelu_mul_bf16(float g, float u) {
  const float z = 0.7978845608028654f * (g + 0.044715f * g * g * g);
  const float ex = __expf(2.f * z);
  const float th = (ex - 1.f) / (ex + 1.f);
  return f2bf(0.5f * g * (1.f + th) * u);
}

__device__ __forceinline__ float bflo(unsigned int u) {
  return __uint_as_float(u << 16);
}
__device__ __forceinline__ float bfhi(unsigned int u) {
  return __uint_as_float(u & 0xFFFF0000u);
}

// ===== prep: cvt x + transpose(Wg,Wu->WguT) + transpose(Wd->WdT) + routing ==
// (identical to round-5..8 passing version; LDS stride 73 = conflict-free)
__global__ __launch_bounds__(512)
void prep_all(const float4* __restrict__ x4, ushort4* __restrict__ xb4,
              const float* __restrict__ Wg, const float* __restrict__ Wu,
              const float* __restrict__ Wd,
              unsigned short* __restrict__ WguT,
              unsigned short* __restrict__ WdT,
              const int* __restrict__ sel, const float* __restrict__ rw,
              int* __restrict__ pair_token, float* __restrict__ pair_weight,
              int* __restrict__ inv,
              int* __restrict__ tile_expert, int* __restrict__ tile_pos) {
  const int bid = blockIdx.x;
  const int tid = threadIdx.x;

  if (bid < CVT_BLKS) {                    // ---- cvt x -> bf16 ----
    int i = bid * 512 + tid;
    const int stride = CVT_BLKS * 512;
#pragma unroll
    for (int q = 0; q < 4; ++q) {
      const float4 v = x4[i];
      ushort4 r;
      r.x = f2bf(v.x); r.y = f2bf(v.y); r.z = f2bf(v.z); r.w = f2bf(v.w);
      xb4[i] = r;
      i += stride;
    }
    return;
  }

  if (bid < CVT_BLKS + GU_BLKS + D_BLKS) { // ---- weight transposes ----
    __shared__ unsigned short Tl[2][64 * 73];
    const int sub = tid >> 8, k = tid & 255;
    const int rr = k >> 2, cb = (k & 3) * 16;
    const int oc = k >> 2, rb = (k & 3) * 16;

    if (bid < CVT_BLKS + GU_BLKS) {        // Wg/Wu -> WguT (g/u interleaved)
      const int t3 = (bid - CVT_BLKS) * 2 + sub;    // [0, 8192)
      const int which = t3 >> 12;                   // 0=gate, 1=up
      const int e = (t3 >> 9) & 7;
      const int tile = t3 & 511;                    // 32 h-tiles x 16 i-tiles
      const int r0 = (tile >> 4) * 64;              // h base
      const int c0 = (tile & 15) * 64;              // i base
      const float* src = (which ? Wu : Wg) + (size_t)e * H_DIM * I_DIM;
      const float4* s4 = (const float4*)(src + (size_t)(r0 + rr) * I_DIM + c0 + cb);
      unsigned short* dl = &Tl[sub][rr * 73 + cb];
#pragma unroll
      for (int q = 0; q < 4; ++q) {
        const float4 v = s4[q];
        dl[q * 4 + 0] = f2bf(v.x); dl[q * 4 + 1] = f2bf(v.y);
        dl[q * 4 + 2] = f2bf(v.z); dl[q * 4 + 3] = f2bf(v.w);
      }
      __syncthreads();
      union { unsigned short us[16]; uint4 u4[2]; } pk;
#pragma unroll
      for (int m = 0; m < 16; ++m) pk.us[m] = Tl[sub][(rb + m) * 73 + oc];
      const int gi = c0 + oc;
      const int orow = (gi >> 4) * 32 + (gi & 15) + which * 16;
      uint4* d4 = (uint4*)(WguT + ((size_t)e * 2048 + orow) * H_DIM + r0 + rb);
      d4[0] = pk.u4[0]; d4[1] = pk.u4[1];
    } else {                               // Wd -> WdT (i'-permuted cols)
      const int t3 = (bid - CVT_BLKS - GU_BLKS) * 2 + sub;  // [0, 4096)
      const int e = t3 >> 9;
      const int tile = t3 & 511;                    // 16 i-tiles x 32 h-tiles
      const int r0 = (tile >> 5) * 64;              // i base
      const int c0 = (tile & 31) * 64;              // h base
      const float* src = Wd + (size_t)e * I_DIM * H_DIM;
      const float4* s4 = (const float4*)(src + (size_t)(r0 + rr) * H_DIM + c0 + cb);
      unsigned short* dl = &Tl[sub][rr * 73 + cb];
#pragma unroll
      for (int q = 0; q < 4; ++q) {
        const float4 v = s4[q];
        dl[q * 4 + 0] = f2bf(v.x); dl[q * 4 + 1] = f2bf(v.y);
        dl[q * 4 + 2] = f2bf(v.z); dl[q * 4 + 3] = f2bf(v.w);
      }
      __syncthreads();
      union { unsigned short us[16]; uint4 u4[2]; } pk;
#pragma unroll
      for (int m = 0; m < 16; ++m) {
        const int il = rb + m;                      // i' local [0,64)
        const int isrc = (il & 32) + ((il & 1) << 4) + ((il >> 1) & 15);
        pk.us[m] = Tl[sub][isrc * 73 + oc];
      }
      const int gh = c0 + oc;
      uint4* d4 = (uint4*)(WdT + ((size_t)e * H_DIM + gh) * I_DIM + r0 + rb);
      d4[0] = pk.u4[0]; d4[1] = pk.u4[1];
    }
    return;
  }

  // ---- routing (single block), BM=128 tiles ----
  __shared__ int cnt[E_NUM], off[E_NUM], fil[E_NUM];
  if (tid < E_NUM) { cnt[tid] = 0; fil[tid] = 0; }
  __syncthreads();
  for (int p = tid; p < NPAIR; p += 512) atomicAdd(&cnt[sel[p]], 1);
  for (int q = tid; q < CAP; q += 512) { pair_token[q] = 0; pair_weight[q] = 0.f; }
  __syncthreads();
  if (tid == 0) {
    int run = 0, idx = 0;
    for (int e = 0; e < E_NUM; ++e) {
      off[e] = run;
      const int nt = (cnt[e] + BM - 1) / BM;
      for (int t = 0; t < nt; ++t) { tile_expert[idx] = e; tile_pos[idx] = run + t * BM; ++idx; }
      run += nt * BM;
    }
    for (; idx < MAX_TILES; ++idx) tile_expert[idx] = -1;
  }
  __syncthreads();
  for (int p = tid; p < NPAIR; p += 512) {
    const int e = sel[p];
    const int pos = off[e] + atomicAdd(&fil[e], 1);
    pair_token[pos] = p >> 1;   // K_SEL == 2
    pair_weight[pos] = rw[p];
    inv[p] = pos;
  }
}

// ====== 128x256 8-wave GEMM, BK=32, 3-slot counted ring, 2 blocks/CU =======
// MODE 0: A = xb gathered by pair_token (K=2048), B = WguT -> a_pair packed u32
// MODE 1: A = a_pair (K=1024, i' order), B = WdT -> d_pair bf16 (w applied)
// The untested cell of the r4..r12 matrix: pipeline depth (3-slot counted
// vmcnt) AND cross-block TLP (72KB LDS -> 2 blocks/CU) simultaneously.
// Per K-step: ds_read 8 frags(slot t%3); stage t+2 -> slot (t+2)%3 (3 gloads/
// thread); vmcnt(3) [t+1 resident] + lgkmcnt(0) BEFORE barrier (slot recycle
// provably race-free); barrier; 16 MFMA. Swizzles: BK=32 staging/read pair
// proven in r10 (0 conflicts); wave layout + epilogues verbatim from r8.
template<int MODE>
__global__ __launch_bounds__(512, 2)
void moe_gemm(const unsigned short* __restrict__ Aop,
              const unsigned short* __restrict__ Bop,
              const int* __restrict__ pair_token,
              const float* __restrict__ pair_weight,
              const int* __restrict__ tile_expert,
              const int* __restrict__ tile_pos,
              unsigned int* __restrict__ a32,
              unsigned short* __restrict__ d_pair) {
  constexpr int KD = (MODE == 0) ? H_DIM : I_DIM;
  constexpr int NT = KD / 32;

  extern __shared__ unsigned short smem[];
  unsigned short* sA = smem;              // 3 slots x 4096 shorts (8 KB)
  unsigned short* sB = smem + 3 * 4096;   // 3 slots x 8192 shorts (16 KB)

  const int bid = blockIdx.x;
  const int mt = bid >> 3;
  const int nt = bid & 7;
  const int e = tile_expert[mt];
  if (e < 0) return;
  const int pbase = tile_pos[mt];

  const int tid = threadIdx.x;
  const int wv = tid >> 6;               // 0..7
  const int lane = tid & 63;
  const int fr = lane & 15;
  const int fq = lane >> 4;
  const int wm = (wv >> 2) * 64;         // 0/64
  const int wn = (wv & 3) * 64;          // 0/64/128/192

  // ---- staging sources (r10's proven BK=32 swizzle): wave wv covers rows
  // wv*16 + (lane>>2); chunk gch = (lane&3) ^ ((lane>>3)&3)  [(row>>1)&3]
  const int rr = lane >> 2;              // 0..15
  const int gch = (lane & 3) ^ ((lane >> 3) & 3);
  const unsigned short* paA;
  const unsigned short* pb[2];
  {
    const int rowA = wv * 16 + rr;       // 0..127
    size_t arow;
    if constexpr (MODE == 0) arow = (size_t)pair_token[pbase + rowA];
    else                     arow = (size_t)(pbase + rowA);
    paA = Aop + arow * KD + gch * 8;
    const unsigned short* Be = Bop + (size_t)e * 2048 * KD;
#pragma unroll
    for (int j = 0; j < 2; ++j)
      pb[j] = Be + (size_t)(nt * 256 + j * 128 + wv * 16 + rr) * KD + gch * 8;
  }

  // ---- LDS read offsets; row = 32 shorts, chunk swizzle fq ^ ((fr>>1)&3)
  const int csw = (fq ^ ((fr >> 1) & 3)) * 8;
  int aoff[4], boff[4];
#pragma unroll
  for (int mf = 0; mf < 4; ++mf) aoff[mf] = (wm + mf * 16 + fr) * 32 + csw;
#pragma unroll
  for (int nf = 0; nf < 4; ++nf) boff[nf] = (wn + nf * 16 + fr) * 32 + csw;

  f32x4 acc[4][4] = {};

#define STAGE(T, S)                                                          \
  {                                                                          \
    async_lds16(paA + (size_t)(T) * 32, sA + (S) * 4096 + wv * 512);         \
    async_lds16(pb[0] + (size_t)(T) * 32, sB + (S) * 8192 + wv * 512);       \
    async_lds16(pb[1] + (size_t)(T) * 32, sB + (S) * 8192 + 4096 + wv * 512);\
  }

  // prologue: slots 0,1 in flight; slot 0 resident (3 newest = slot1's)
  STAGE(0, 0);
  STAGE(1, 1);
  asm volatile("s_waitcnt vmcnt(3)" ::: "memory");
  __builtin_amdgcn_s_barrier();
  __builtin_amdgcn_sched_barrier(0);

  for (int t = 0; t < NT; ++t) {
    const int s = t % 3;
    const unsigned short* As = sA + s * 4096;
    const unsigned short* Bs = sB + s * 8192;
    s16x8 aF[4], bF[4];
#pragma unroll
    for (int mf = 0; mf < 4; ++mf) aF[mf] = *(const s16x8*)&As[aoff[mf]];
#pragma unroll
    for (int nf = 0; nf < 4; ++nf) bF[nf] = *(const s16x8*)&Bs[boff[nf]];
    if (t + 2 < NT) {
      STAGE(t + 2, (t + 2) % 3);
      asm volatile("s_waitcnt vmcnt(3) lgkmcnt(0)" ::: "memory");
    } else if (t + 1 < NT) {
      asm volatile("s_waitcnt vmcnt(0) lgkmcnt(0)" ::: "memory");
    } else {
      asm volatile("s_waitcnt lgkmcnt(0)" ::: "memory");
    }
    __builtin_amdgcn_s_barrier();
    __builtin_amdgcn_sched_barrier(0);
    __builtin_amdgcn_s_setprio(1);
#pragma unroll
    for (int mf = 0; mf < 4; ++mf)
#pragma unroll
      for (int nf = 0; nf < 4; ++nf)
        acc[mf][nf] = mfma_bf16(aF[mf], bF[nf], acc[mf][nf]);
    __builtin_amdgcn_s_setprio(0);
  }
#undef STAGE

  if constexpr (MODE == 0) {
    // packed epilogue (verbatim r8): (nf0,nf1)=(g,u) of i, (nf2,nf3) of i+16
    const int cidx = (nt * 4 + (wn >> 6)) * 16 + fr;   // dword index in row
#pragma unroll
    for (int mf = 0; mf < 4; ++mf)
#pragma unroll
      for (int jj = 0; jj < 4; ++jj) {
        const int row = pbase + wm + mf * 16 + fq * 4 + jj;
        const unsigned int h0 = gelu_mul_bf16(acc[mf][0][jj], acc[mf][1][jj]);
        const unsigned int h1 = gelu_mul_bf16(acc[mf][2][jj], acc[mf][3][jj]);
        a32[(size_t)row * (I_DIM / 2) + cidx] = h0 | (h1 << 16);
      }
  } else {
    // plain bf16 stores of w*d into d_pair (combine sums the two experts)
#pragma unroll
    for (int mf = 0; mf < 4; ++mf)
#pragma unroll
      for (int jj = 0; jj < 4; ++jj) {
        const int prow = pbase + wm + mf * 16 + fq * 4 + jj;
        const float w = pair_weight[prow];
        unsigned short* dp = d_pair + (size_t)prow * H_DIM + nt * 256 + wn + fr;
#pragma unroll
        for (int nf = 0; nf < 4; ++nf)
          dp[nf * 16] = f2bf(w * acc[mf][nf][jj]);
      }
  }
}

// ========================= combine: out[t] = d[p0] + d[p1] =================
__global__ __launch_bounds__(256)
void combine(const unsigned short* __restrict__ d_pair,
             const int* __restrict__ inv,
             float* __restrict__ out) {
  const int tid = threadIdx.x;
  const int tok = blockIdx.x * 2 + (tid >> 7);
  const int ln = tid & 127;
  const int p0 = inv[2 * tok], p1 = inv[2 * tok + 1];
  const uint4* r0 = (const uint4*)(d_pair + (size_t)p0 * H_DIM);
  const uint4* r1 = (const uint4*)(d_pair + (size_t)p1 * H_DIM);
  float4* o = (float4*)(out + (size_t)tok * H_DIM);
#pragma unroll
  for (int j = 0; j < 2; ++j) {
    const int c = ln + j * 128;               // uint4 index, 256 per row
    const uint4 a = r0[c];
    const uint4 b = r1[c];
    float4 fa, fb;
    fa.x = bflo(a.x) + bflo(b.x); fa.y = bfhi(a.x) + bfhi(b.x);
    fa.z = bflo(a.y) + bflo(b.y); fa.w = bfhi(a.y) + bfhi(b.y);
    fb.x = bflo(a.z) + bflo(b.z); fb.y = bfhi(a.z) + bfhi(b.z);
    fb.z = bflo(a.w) + bflo(b.w); fb.w = bfhi(a.w) + bfhi(b.w);
    o[2 * c] = fa;
    o[2 * c + 1] = fb;
  }
}

// ================================= launch ==================================
extern "C" void kernel_launch(void* const* d_in, const int* in_sizes, int n_in,
                              void* d_out, int out_size, void* d_ws, size_t ws_size,
                              hipStream_t stream) {
  const float* x  = (const float*)d_in[0];
  const float* Wg = (const float*)d_in[1];
  const float* Wu = (const float*)d_in[2];
  const float* Wd = (const float*)d_in[3];
  const int*   sel = (const int*)d_in[4];
  const float* rw  = (const float*)d_in[5];
  float* out = (float*)d_out;

  char* base = (char*)d_ws;
  size_t off = 0;
  auto take = [&](size_t bytes) { char* p = base + off; off += bytes; return p; };
  unsigned short* xb     = (unsigned short*)take((size_t)T_TOK * H_DIM * 2);
  unsigned short* WguT   = (unsigned short*)take((size_t)E_NUM * 2048 * H_DIM * 2);
  unsigned short* WdT    = (unsigned short*)take((size_t)E_NUM * H_DIM * I_DIM * 2);
  unsigned short* a_pair = (unsigned short*)take((size_t)CAP * I_DIM * 2);
  unsigned short* d_pair = (unsigned short*)take((size_t)CAP * H_DIM * 2);
  int*   pair_token  = (int*)take(CAP * 4);
  float* pair_weight = (float*)take(CAP * 4);
  int*   inv         = (int*)take(NPAIR * 4);
  int*   tile_expert = (int*)take(512);
  int*   tile_pos    = (int*)take(512);
  (void)off;

  hipFuncSetAttribute((const void*)&moe_gemm<0>,
                      hipFuncAttributeMaxDynamicSharedMemorySize, 73728);
  hipFuncSetAttribute((const void*)&moe_gemm<1>,
                      hipFuncAttributeMaxDynamicSharedMemorySize, 73728);

  prep_all<<<PREP_BLKS, 512, 0, stream>>>(
      (const float4*)x, (ushort4*)xb, Wg, Wu, Wd, WguT, WdT, sel, rw,
      pair_token, pair_weight, inv, tile_expert, tile_pos);

  moe_gemm<0><<<NTB2, 512, 73728, stream>>>(
      xb, WguT, pair_token, pair_weight, tile_expert, tile_pos,
      (unsigned int*)a_pair, nullptr);

  moe_gemm<1><<<NTB2, 512, 73728, stream>>>(
      a_pair, WdT, pair_token, pair_weight, tile_expert, tile_pos,
      nullptr, d_pair);

  combine<<<T_TOK / 2, 256, 0, stream>>>(d_pair, inv, out);
}